// Round 2
// baseline (207.513 us; speedup 1.0000x reference)
//
#include <hip/hip_runtime.h>
#include <hip/hip_bf16.h>

typedef __bf16 bf16x8 __attribute__((ext_vector_type(8)));
typedef __bf16 bf16x4 __attribute__((ext_vector_type(4)));
typedef float f32x4 __attribute__((ext_vector_type(4)));

#define SLEN 2048
#define NHEADS 16
#define HDIM 64

__device__ __forceinline__ void async_copy16(const __bf16* g, void* l) {
    __builtin_amdgcn_global_load_lds(
        (const __attribute__((address_space(1))) void*)g,
        (__attribute__((address_space(3))) void*)l, 16, 0, 0);
}

// ---------------- cast hidden fp32 -> bf16 ----------------
__global__ __launch_bounds__(256) void cast_f32_bf16(const float* __restrict__ in,
                                                     __bf16* __restrict__ out, int n4) {
    int i = blockIdx.x * 256 + threadIdx.x;
    if (i < n4) {
        float4 v = reinterpret_cast<const float4*>(in)[i];
        bf16x4 o = { (__bf16)v.x, (__bf16)v.y, (__bf16)v.z, (__bf16)v.w };
        reinterpret_cast<bf16x4*>(out)[i] = o;
    }
}

// ---------------- transpose + cast: W[K][N] fp32 -> Wt[N][K] bf16 ----------------
__global__ __launch_bounds__(256) void transpose_cast(const float* __restrict__ W,
                                                      __bf16* __restrict__ Wt,
                                                      int K, int N) {
    __shared__ float tile[32][33];
    int n0 = blockIdx.x * 32, k0 = blockIdx.y * 32;
    int tx = threadIdx.x, ty = threadIdx.y;
    #pragma unroll
    for (int i = ty; i < 32; i += 8)
        tile[i][tx] = W[(size_t)(k0 + i) * N + n0 + tx];
    __syncthreads();
    #pragma unroll
    for (int i = ty; i < 32; i += 8)
        Wt[(size_t)(n0 + i) * K + k0 + tx] = (__bf16)tile[tx][i];
}

// ---------------- GEMM: C[M][N] = A[M][K] @ Bt[N][K]^T  (bf16 in, fp32 acc) ---------
// m97 structure: global_load_lds width-16 staging, unpadded LDS with XOR bank swizzle.
// epi==0: Cf[row][col] = acc + bias[col]          (fp32 out)
// epi==1: + fused RoPE on Q,K parts; split into Q/K/V bf16 [B][H][S][D]
__global__ __launch_bounds__(256) void gemm_bt(const __bf16* __restrict__ A,
                                               const __bf16* __restrict__ Bt,
                                               const float* __restrict__ bias,
                                               const float* __restrict__ rope,
                                               float* __restrict__ Cf,
                                               __bf16* __restrict__ Cq,
                                               __bf16* __restrict__ Ck,
                                               __bf16* __restrict__ Cv,
                                               int M, int N, int K, int epi) {
    __shared__ __align__(16) __bf16 As[128 * 32];
    __shared__ __align__(16) __bf16 Bs[128 * 32];

    int nb = N >> 7;
    int bx = blockIdx.x % nb;
    int by = blockIdx.x / nb;
    int row0 = by * 128, col0 = bx * 128;

    int tid = threadIdx.x;
    int wave = tid >> 6, lane = tid & 63;
    int quad = lane >> 4, lrow = lane & 15;
    int wm = wave >> 1, wn = wave & 1;

    // staging: thread tid owns LDS bytes [tid*16, tid*16+16) = row r1, elem slot kk.
    // slot kk holds global column kk ^ swz(r1)  (swz = ((r1>>1)&3)*8, 16B-chunk xor)
    int r1 = tid >> 2;
    int kk = (tid & 3) * 8;
    int kg = kk ^ (((r1 >> 1) & 3) * 8);
    const __bf16* Ap = A + (size_t)(row0 + r1) * K + kg;
    const __bf16* Bp = Bt + (size_t)(col0 + r1) * K + kg;
    char* as_lo = (char*)As + wave * 1024;
    char* bs_lo = (char*)Bs + wave * 1024;

    f32x4 acc[4][4];
    f32x4 zero = {0.f, 0.f, 0.f, 0.f};
    #pragma unroll
    for (int i = 0; i < 4; i++)
        #pragma unroll
        for (int j = 0; j < 4; j++) acc[i][j] = zero;

    // fragment-read swizzled chunk offset (depends only on lrow)
    int sA = (quad ^ ((lrow >> 1) & 3)) * 8;

    for (int k0 = 0; k0 < K; k0 += 32) {
        __syncthreads();
        async_copy16(Ap + k0, as_lo);
        async_copy16(Ap + (size_t)64 * K + k0, as_lo + 4096);
        async_copy16(Bp + k0, bs_lo);
        async_copy16(Bp + (size_t)64 * K + k0, bs_lo + 4096);
        __syncthreads();

        bf16x8 af[4], bfr[4];
        #pragma unroll
        for (int i = 0; i < 4; i++)
            af[i] = *reinterpret_cast<const bf16x8*>(&As[(wm * 64 + i * 16 + lrow) * 32 + sA]);
        #pragma unroll
        for (int j = 0; j < 4; j++)
            bfr[j] = *reinterpret_cast<const bf16x8*>(&Bs[(wn * 64 + j * 16 + lrow) * 32 + sA]);
        #pragma unroll
        for (int i = 0; i < 4; i++)
            #pragma unroll
            for (int j = 0; j < 4; j++)
                acc[i][j] = __builtin_amdgcn_mfma_f32_16x16x32_bf16(af[i], bfr[j], acc[i][j], 0, 0, 0);
    }

    // epilogue: D row = quad*4 + reg, col = lrow within each 16x16 tile
    int part = col0 >> 10;          // block-uniform (128 | 1024)
    bool do_rope = (epi == 1) && (part < 2);
    #pragma unroll
    for (int i = 0; i < 4; i++) {
        int rowb = row0 + wm * 64 + i * 16 + quad * 4;
        #pragma unroll
        for (int j = 0; j < 4; j++) {
            int col = col0 + wn * 64 + j * 16 + lrow;
            float bsv = bias[col];
            int d = col & 63;
            #pragma unroll
            for (int r = 0; r < 4; r++) {
                int row = rowb + r;
                float v = acc[i][j][r] + bsv;
                if (do_rope) {
                    int pos = row & 255;
                    int p = d >> 1;
                    float c  = rope[(pos * 32 + p) * 2];
                    float sn = rope[(pos * 32 + p) * 2 + 1];
                    float other = __shfl_xor(v, 1, 64);
                    v = (d & 1) ? fmaf(v, c, other * sn) : fmaf(v, c, -other * sn);
                }
                if (epi == 0) {
                    Cf[(size_t)row * N + col] = v;
                } else {
                    int h = (col >> 6) & 15;
                    int b = row >> 11;
                    int s = row & 2047;
                    __bf16* dst = (part == 0) ? Cq : ((part == 1) ? Ck : Cv);
                    dst[((size_t)(b * NHEADS + h) * SLEN + s) * HDIM + d] = (__bf16)v;
                }
            }
        }
    }
}

// ---------------- windowed flash attention (64-key chunks) ----------------
// grid: B*H*(S/64) blocks; block = 4 waves; wave handles 16 queries.
__global__ __launch_bounds__(256) void attn_kernel(const __bf16* __restrict__ Q,
                                                   const __bf16* __restrict__ Kt,
                                                   const __bf16* __restrict__ V,
                                                   __bf16* __restrict__ O) {
    __shared__ __align__(16) __bf16 Vt[64][72];       // [d][key] for PV B-operand
    __shared__ __align__(16) __bf16 Pl[4][16][72];    // per-wave P roundtrip

    int qt = blockIdx.x & 31;
    int bh = blockIdx.x >> 5;
    int q0 = qt * 64;
    const __bf16* Qbh = Q + (size_t)bh * SLEN * HDIM;
    const __bf16* Kbh = Kt + (size_t)bh * SLEN * HDIM;
    const __bf16* Vbh = V + (size_t)bh * SLEN * HDIM;

    int tid = threadIdx.x;
    int wave = tid >> 6, lane = tid & 63;
    int quad = lane >> 4, lrow = lane & 15;
    int wq0 = q0 + wave * 16;

    // Q fragments (A-operand): lane holds Q[lrow][quad*8 + j] (+32 for second half)
    bf16x8 qa0 = *reinterpret_cast<const bf16x8*>(Qbh + (size_t)(wq0 + lrow) * HDIM + quad * 8);
    bf16x8 qa1 = *reinterpret_cast<const bf16x8*>(Qbh + (size_t)(wq0 + lrow) * HDIM + 32 + quad * 8);

    f32x4 zero = {0.f, 0.f, 0.f, 0.f};
    f32x4 acc[4];
    #pragma unroll
    for (int t = 0; t < 4; t++) acc[t] = zero;
    float m_i[4], l_i[4];
    #pragma unroll
    for (int r = 0; r < 4; r++) { m_i[r] = -1e30f; l_i[r] = 0.f; }

    int kstart = q0 - 128; if (kstart < 0) kstart = 0;
    int kend = q0 + 63 + 128 + 1; if (kend > SLEN) kend = SLEN;
    // kstart/kend are multiples of 64 for all blocks

    for (int kc = kstart; kc < kend; kc += 64) {
        __syncthreads();
        // stage 64-key V chunk transposed: Vt[d][key]
        {
            int keyl = tid >> 2;
            int db = (tid & 3) * 16;
            const __bf16* vp = Vbh + (size_t)(kc + keyl) * HDIM + db;
            bf16x8 v0 = *reinterpret_cast<const bf16x8*>(vp);
            bf16x8 v1 = *reinterpret_cast<const bf16x8*>(vp + 8);
            #pragma unroll
            for (int i = 0; i < 8; i++) {
                Vt[db + i][keyl] = v0[i];
                Vt[db + 8 + i][keyl] = v1[i];
            }
        }
        __syncthreads();

        // QK^T for four 16-key subtiles
        f32x4 cs[4];
        #pragma unroll
        for (int sub = 0; sub < 4; sub++) {
            cs[sub] = zero;
            const __bf16* krow = Kbh + (size_t)(kc + sub * 16 + lrow) * HDIM;
            bf16x8 kba = *reinterpret_cast<const bf16x8*>(krow + quad * 8);
            bf16x8 kbb = *reinterpret_cast<const bf16x8*>(krow + 32 + quad * 8);
            cs[sub] = __builtin_amdgcn_mfma_f32_16x16x32_bf16(qa0, kba, cs[sub], 0, 0, 0);
            cs[sub] = __builtin_amdgcn_mfma_f32_16x16x32_bf16(qa1, kbb, cs[sub], 0, 0, 0);
        }

        // online softmax per query row (row = quad*4 + r)
        #pragma unroll
        for (int r = 0; r < 4; r++) {
            int q = wq0 + quad * 4 + r;
            float sc[4];
            bool vd[4];
            #pragma unroll
            for (int sub = 0; sub < 4; sub++) {
                int key = kc + sub * 16 + lrow;
                vd[sub] = (key >= q - 128) && (key <= q + 128);
                sc[sub] = vd[sub] ? cs[sub][r] * 0.125f : -1e30f;
            }
            float rm = fmaxf(fmaxf(sc[0], sc[1]), fmaxf(sc[2], sc[3]));
            #pragma unroll
            for (int off = 1; off < 16; off <<= 1) rm = fmaxf(rm, __shfl_xor(rm, off, 64));
            float mnew = fmaxf(m_i[r], rm);
            float alpha = __expf(m_i[r] - mnew);
            float p[4], rs = 0.f;
            #pragma unroll
            for (int sub = 0; sub < 4; sub++) {
                p[sub] = vd[sub] ? __expf(sc[sub] - mnew) : 0.0f;
                rs += p[sub];
            }
            #pragma unroll
            for (int off = 1; off < 16; off <<= 1) rs += __shfl_xor(rs, off, 64);
            l_i[r] = l_i[r] * alpha + rs;
            m_i[r] = mnew;
            #pragma unroll
            for (int t = 0; t < 4; t++) acc[t][r] *= alpha;
            #pragma unroll
            for (int sub = 0; sub < 4; sub++)
                Pl[wave][quad * 4 + r][sub * 16 + lrow] = (__bf16)p[sub];
        }
        // wave-local LDS roundtrip: ensure P writes complete before frag reads
        asm volatile("s_waitcnt lgkmcnt(0)" ::: "memory");

        // P A-fragments: lane holds P[lrow][quad*8 + j] (keys 0-31), +32 (keys 32-63)
        bf16x8 ap0 = *reinterpret_cast<const bf16x8*>(&Pl[wave][lrow][quad * 8]);
        bf16x8 ap1 = *reinterpret_cast<const bf16x8*>(&Pl[wave][lrow][32 + quad * 8]);
        #pragma unroll
        for (int t = 0; t < 4; t++) {
            bf16x8 bv0 = *reinterpret_cast<const bf16x8*>(&Vt[t * 16 + lrow][quad * 8]);
            bf16x8 bv1 = *reinterpret_cast<const bf16x8*>(&Vt[t * 16 + lrow][32 + quad * 8]);
            acc[t] = __builtin_amdgcn_mfma_f32_16x16x32_bf16(ap0, bv0, acc[t], 0, 0, 0);
            acc[t] = __builtin_amdgcn_mfma_f32_16x16x32_bf16(ap1, bv1, acc[t], 0, 0, 0);
        }
    }

    // epilogue: O[q][d] = acc / l ; write bf16 [B][S][H*D]
    int b = bh >> 4, h = bh & 15;
    #pragma unroll
    for (int r = 0; r < 4; r++) {
        int stok = q0 + wave * 16 + quad * 4 + r;
        float inv = 1.0f / l_i[r];
        size_t base = ((size_t)b * SLEN + stok) * 1024 + h * HDIM;
        #pragma unroll
        for (int t = 0; t < 4; t++) {
            O[base + t * 16 + lrow] = (__bf16)(acc[t][r] * inv);
        }
    }
}

extern "C" void kernel_launch(void* const* d_in, const int* in_sizes, int n_in,
                              void* d_out, int out_size, void* d_ws, size_t ws_size,
                              hipStream_t stream) {
    const float* hidden = (const float*)d_in[0];   // [2,2048,1024]
    const float* Wqkv   = (const float*)d_in[1];   // [1024,3072]
    const float* bqkv   = (const float*)d_in[2];   // [3072]
    const float* Wo     = (const float*)d_in[3];   // [1024,1024]
    const float* bo     = (const float*)d_in[4];   // [1024]
    const float* rope   = (const float*)d_in[5];   // [256,32,2]
    float* out = (float*)d_out;                    // [2,2048,1024] fp32

    char* ws = (char*)d_ws;
    __bf16* A1  = (__bf16*)(ws);                   //  8 MiB: hidden bf16 [4096][1024]
    __bf16* Wt  = (__bf16*)(ws + 8388608);         //  6 MiB: Wqkv^T bf16 [3072][1024]
    __bf16* Wot = (__bf16*)(ws + 14680064);        //  2 MiB: Wo^T bf16 [1024][1024]
    __bf16* Qb  = (__bf16*)(ws + 16777216);        //  8 MiB: Q [B][H][S][64]
    __bf16* Kb  = (__bf16*)(ws + 25165824);        //  8 MiB: K
    __bf16* Vb  = (__bf16*)(ws + 33554432);        //  8 MiB: V
    __bf16* AO  = (__bf16*)(ws + 41943040);        //  8 MiB: attn out [4096][1024]

    cast_f32_bf16<<<4096, 256, 0, stream>>>(hidden, A1, 1048576);
    transpose_cast<<<dim3(96, 32), dim3(32, 8), 0, stream>>>(Wqkv, Wt, 1024, 3072);
    transpose_cast<<<dim3(32, 32), dim3(32, 8), 0, stream>>>(Wo, Wot, 1024, 1024);

    // QKV projection (+fused RoPE): [4096,1024] @ [1024,3072] -> Q/K/V [B][H][S][64]
    gemm_bt<<<32 * 24, 256, 0, stream>>>(A1, Wt, bqkv, rope, nullptr, Qb, Kb, Vb,
                                         4096, 3072, 1024, 1);
    // windowed attention -> AO [4096][1024] bf16
    attn_kernel<<<2 * 16 * 32, 256, 0, stream>>>(Qb, Kb, Vb, AO);
    // output projection: [4096,1024] @ [1024,1024] + bias -> d_out fp32
    gemm_bt<<<32 * 8, 256, 0, stream>>>(AO, Wot, bo, rope, out, nullptr, nullptr, nullptr,
                                        4096, 1024, 1024, 0);
}

// Round 3
// 201.006 us; speedup vs baseline: 1.0324x; 1.0324x over previous
//
#include <hip/hip_runtime.h>
#include <hip/hip_bf16.h>

typedef __bf16 bf16x8 __attribute__((ext_vector_type(8)));
typedef __bf16 bf16x4 __attribute__((ext_vector_type(4)));
typedef float f32x4 __attribute__((ext_vector_type(4)));

#define SLEN 2048
#define NHEADS 16
#define HDIM 64

// ---------------- cast hidden fp32 -> bf16 ----------------
__global__ __launch_bounds__(256) void cast_f32_bf16(const float* __restrict__ in,
                                                     __bf16* __restrict__ out, int n4) {
    int i = blockIdx.x * 256 + threadIdx.x;
    if (i < n4) {
        float4 v = reinterpret_cast<const float4*>(in)[i];
        bf16x4 o = { (__bf16)v.x, (__bf16)v.y, (__bf16)v.z, (__bf16)v.w };
        reinterpret_cast<bf16x4*>(out)[i] = o;
    }
}

// ---------------- transpose + cast: W[K][N] fp32 -> Wt[N][K] bf16 ----------------
__global__ __launch_bounds__(256) void transpose_cast(const float* __restrict__ W,
                                                      __bf16* __restrict__ Wt,
                                                      int K, int N) {
    __shared__ float tile[32][33];
    int n0 = blockIdx.x * 32, k0 = blockIdx.y * 32;
    int tx = threadIdx.x, ty = threadIdx.y;
    #pragma unroll
    for (int i = ty; i < 32; i += 8)
        tile[i][tx] = W[(size_t)(k0 + i) * N + n0 + tx];
    __syncthreads();
    #pragma unroll
    for (int i = ty; i < 32; i += 8)
        Wt[(size_t)(n0 + i) * K + k0 + tx] = (__bf16)tile[tx][i];
}

// ---------------- GEMM: C[M][N] = A[M][K] @ Bt[N][K]^T  (bf16 in, fp32 acc) ---------
// R1 register-prefetch staging + R2 XOR bank swizzle (0 conflicts).
// TN = 128 (QKV, 2x2 waves) or 64 (out-proj, denser grid).
// epi==0: Cf[row][col] = acc + bias[col]          (fp32 out)
// epi==1: + fused RoPE on Q,K parts; split into Q/K/V bf16 [B][H][S][D]
template <int TN>
__global__ __launch_bounds__(256) void gemm_bt(const __bf16* __restrict__ A,
                                               const __bf16* __restrict__ Bt,
                                               const float* __restrict__ bias,
                                               const float* __restrict__ rope,
                                               float* __restrict__ Cf,
                                               __bf16* __restrict__ Cq,
                                               __bf16* __restrict__ Ck,
                                               __bf16* __restrict__ Cv,
                                               int M, int N, int K, int epi) {
    constexpr int JN = TN / 32;   // n-frags per wave
    __shared__ __align__(16) __bf16 As[128 * 32];
    __shared__ __align__(16) __bf16 Bs[TN * 32];

    int nb = N / TN;
    int bx = blockIdx.x % nb;
    int by = blockIdx.x / nb;
    int row0 = by * 128, col0 = bx * TN;

    int tid = threadIdx.x;
    int wave = tid >> 6, lane = tid & 63;
    int quad = lane >> 4, lrow = lane & 15;
    int wm = wave >> 1, wn = wave & 1;

    // staging: thread owns row r1, 16B slot kk; slot kk holds global col kk^swz(r1)
    int r1 = tid >> 2;
    int kk = (tid & 3) * 8;
    int kg = kk ^ (((r1 >> 1) & 3) * 8);
    const __bf16* Ap = A + (size_t)(row0 + r1) * K + kg;
    const __bf16* Bp = Bt + (size_t)(col0 + r1) * K + kg;

    f32x4 acc[4][JN];
    f32x4 zero = {0.f, 0.f, 0.f, 0.f};
    #pragma unroll
    for (int i = 0; i < 4; i++)
        #pragma unroll
        for (int j = 0; j < JN; j++) acc[i][j] = zero;

    int sA = (quad ^ ((lrow >> 1) & 3)) * 8;   // swizzled chunk offset for frag reads

    for (int k0 = 0; k0 < K; k0 += 32) {
        // global -> registers (latency overlaps barrier 1 + prior MFMAs)
        bf16x8 a0 = *reinterpret_cast<const bf16x8*>(Ap + k0);
        bf16x8 a1 = *reinterpret_cast<const bf16x8*>(Ap + (size_t)64 * K + k0);
        bf16x8 b0 = *reinterpret_cast<const bf16x8*>(Bp + k0);
        bf16x8 b1;
        if (TN == 128) b1 = *reinterpret_cast<const bf16x8*>(Bp + (size_t)64 * K + k0);
        __syncthreads();
        *reinterpret_cast<bf16x8*>(&As[r1 * 32 + kk]) = a0;
        *reinterpret_cast<bf16x8*>(&As[(r1 + 64) * 32 + kk]) = a1;
        *reinterpret_cast<bf16x8*>(&Bs[r1 * 32 + kk]) = b0;
        if (TN == 128) *reinterpret_cast<bf16x8*>(&Bs[(r1 + 64) * 32 + kk]) = b1;
        __syncthreads();

        bf16x8 af[4], bfr[JN];
        #pragma unroll
        for (int i = 0; i < 4; i++)
            af[i] = *reinterpret_cast<const bf16x8*>(&As[(wm * 64 + i * 16 + lrow) * 32 + sA]);
        #pragma unroll
        for (int j = 0; j < JN; j++)
            bfr[j] = *reinterpret_cast<const bf16x8*>(&Bs[(wn * (TN / 2) + j * 16 + lrow) * 32 + sA]);
        #pragma unroll
        for (int i = 0; i < 4; i++)
            #pragma unroll
            for (int j = 0; j < JN; j++)
                acc[i][j] = __builtin_amdgcn_mfma_f32_16x16x32_bf16(af[i], bfr[j], acc[i][j], 0, 0, 0);
    }

    int part = col0 >> 10;          // block-uniform
    bool do_rope = (epi == 1) && (part < 2);
    #pragma unroll
    for (int i = 0; i < 4; i++) {
        int rowb = row0 + wm * 64 + i * 16 + quad * 4;
        #pragma unroll
        for (int j = 0; j < JN; j++) {
            int col = col0 + wn * (TN / 2) + j * 16 + lrow;
            float bsv = bias[col];
            int d = col & 63;
            #pragma unroll
            for (int r = 0; r < 4; r++) {
                int row = rowb + r;
                float v = acc[i][j][r] + bsv;
                if (do_rope) {
                    int pos = row & 255;
                    int p = d >> 1;
                    float c  = rope[(pos * 32 + p) * 2];
                    float sn = rope[(pos * 32 + p) * 2 + 1];
                    float other = __shfl_xor(v, 1, 64);
                    v = (d & 1) ? fmaf(v, c, other * sn) : fmaf(v, c, -other * sn);
                }
                if (epi == 0) {
                    Cf[(size_t)row * N + col] = v;
                } else {
                    int h = (col >> 6) & 15;
                    int b = row >> 11;
                    int s = row & 2047;
                    __bf16* dst = (part == 0) ? Cq : ((part == 1) ? Ck : Cv);
                    dst[((size_t)(b * NHEADS + h) * SLEN + s) * HDIM + d] = (__bf16)v;
                }
            }
        }
    }
}

// ---------------- windowed attention v3: no online max, no loop barriers ----------
// grid: BH(32) x qtiles(32); block = 4 waves; wave owns 16 queries.
// S^T = K.Q^T (both natural row loads); P packed to LDS (8B); O^T = V^T.P^T;
// row-sums via one MFMA with A=ones.
__global__ __launch_bounds__(256) void attn_kernel(const __bf16* __restrict__ Q,
                                                   const __bf16* __restrict__ K,
                                                   const __bf16* __restrict__ V,
                                                   __bf16* __restrict__ O) {
    __shared__ __align__(16) __bf16 Vt[64][328];     // V^T for the block's 320-key union
    __shared__ __align__(16) __bf16 Pl[4][16][40];   // per-wave P[q][key-chunk]

    int qt = blockIdx.x & 31;
    int bh = blockIdx.x >> 5;
    int q0 = qt * 64;
    int kbase0 = q0 - 128;
    const __bf16* Qbh = Q + (size_t)bh * SLEN * HDIM;
    const __bf16* Kbh = K + (size_t)bh * SLEN * HDIM;
    const __bf16* Vbh = V + (size_t)bh * SLEN * HDIM;

    int tid = threadIdx.x;
    int wave = tid >> 6, lane = tid & 63;
    int quad = lane >> 4, lrow = lane & 15;
    int wq0 = q0 + wave * 16;

    // ---- stage V^T once: wave handles d-slice [wave*16, wave*16+16), 64 keys/iter
    {
        int dchunk = wave * 16;
        #pragma unroll
        for (int k = 0; k < 5; k++) {
            int off = k * 64 + lane;                 // 0..319
            int krow = kbase0 + off;
            krow = min(max(krow, 0), SLEN - 1);      // clamp: finite data, masked later
            const __bf16* vp = Vbh + (size_t)krow * HDIM + dchunk;
            bf16x8 v0 = *reinterpret_cast<const bf16x8*>(vp);
            bf16x8 v1 = *reinterpret_cast<const bf16x8*>(vp + 8);
            #pragma unroll
            for (int i = 0; i < 8; i++) {
                Vt[dchunk + i][off] = v0[i];
                Vt[dchunk + 8 + i][off] = v1[i];
            }
        }
    }

    // Q B-fragments (loop-invariant): lane holds Q[wq0+lrow][quad*8+j]
    bf16x8 qb0 = *reinterpret_cast<const bf16x8*>(Qbh + (size_t)(wq0 + lrow) * HDIM + quad * 8);
    bf16x8 qb1 = *reinterpret_cast<const bf16x8*>(Qbh + (size_t)(wq0 + lrow) * HDIM + 32 + quad * 8);

    __syncthreads();   // Vt ready; no barriers after this point

    f32x4 zero = {0.f, 0.f, 0.f, 0.f};
    f32x4 acc[4], acc_l = zero;
    #pragma unroll
    for (int t = 0; t < 4; t++) acc[t] = zero;

    bf16x8 ones = { (__bf16)1.f, (__bf16)1.f, (__bf16)1.f, (__bf16)1.f,
                    (__bf16)1.f, (__bf16)1.f, (__bf16)1.f, (__bf16)1.f };

    // wave-uniform chunk range (32-key chunks, rel. to kbase0)
    int cbeg = wave >> 1;
    if (q0 < 128) { int e = (128 - q0) >> 5; if (e > cbeg) cbeg = e; }
    int cend = (16 * wave + 271) >> 5;
    { int e = (2175 - q0) >> 5; if (e < cend) cend = e; }

    for (int c = cbeg; c <= cend; c++) {
        int kb = kbase0 + c * 32;
        int loc = c * 32;

        // S^T = K . Q^T for two 16-key subtiles
        f32x4 st[2];
        #pragma unroll
        for (int sub = 0; sub < 2; sub++) {
            int kr = kb + sub * 16 + lrow;
            int krc = min(max(kr, 0), SLEN - 1);
            const __bf16* kp = Kbh + (size_t)krc * HDIM;
            bf16x8 ka0 = *reinterpret_cast<const bf16x8*>(kp + quad * 8);
            bf16x8 ka1 = *reinterpret_cast<const bf16x8*>(kp + 32 + quad * 8);
            st[sub] = __builtin_amdgcn_mfma_f32_16x16x32_bf16(ka0, qb0, zero, 0, 0, 0);
            st[sub] = __builtin_amdgcn_mfma_f32_16x16x32_bf16(ka1, qb1, st[sub], 0, 0, 0);
        }

        // mask + exp (no max subtraction: scores bounded), pack 4 keys -> 8B LDS write
        int q = wq0 + lrow;
        #pragma unroll
        for (int sub = 0; sub < 2; sub++) {
            bf16x4 pk;
            #pragma unroll
            for (int r = 0; r < 4; r++) {
                int key = kb + sub * 16 + quad * 4 + r;
                int rel = key - q;
                bool valid = (rel >= -128) && (rel <= 128) && (key >= 0) && (key < SLEN);
                float p = valid ? __expf(st[sub][r] * 0.125f) : 0.0f;
                pk[r] = (__bf16)p;
            }
            *reinterpret_cast<bf16x4*>(&Pl[wave][lrow][sub * 16 + quad * 4]) = pk;
        }
        asm volatile("s_waitcnt lgkmcnt(0)" ::: "memory");  // wave-local P roundtrip

        // P B-fragment (natural 16B read), PV as O^T = V^T . P^T, l via A=ones
        bf16x8 bp = *reinterpret_cast<const bf16x8*>(&Pl[wave][lrow][quad * 8]);
        acc_l = __builtin_amdgcn_mfma_f32_16x16x32_bf16(ones, bp, acc_l, 0, 0, 0);
        #pragma unroll
        for (int t = 0; t < 4; t++) {
            bf16x8 va = *reinterpret_cast<const bf16x8*>(&Vt[t * 16 + lrow][loc + quad * 8]);
            acc[t] = __builtin_amdgcn_mfma_f32_16x16x32_bf16(va, bp, acc[t], 0, 0, 0);
        }
    }

    // epilogue: lane holds O^T[d=t*16+quad*4+r][q=lrow]; l[q] = acc_l[0]
    float inv = 1.0f / acc_l[0];
    int b = bh >> 4, h = bh & 15;
    int q = wq0 + lrow;
    size_t base = ((size_t)b * SLEN + q) * 1024 + h * HDIM;
    #pragma unroll
    for (int t = 0; t < 4; t++) {
        bf16x4 o;
        #pragma unroll
        for (int r = 0; r < 4; r++) o[r] = (__bf16)(acc[t][r] * inv);
        *reinterpret_cast<bf16x4*>(&O[base + t * 16 + quad * 4]) = o;
    }
}

extern "C" void kernel_launch(void* const* d_in, const int* in_sizes, int n_in,
                              void* d_out, int out_size, void* d_ws, size_t ws_size,
                              hipStream_t stream) {
    const float* hidden = (const float*)d_in[0];   // [2,2048,1024]
    const float* Wqkv   = (const float*)d_in[1];   // [1024,3072]
    const float* bqkv   = (const float*)d_in[2];   // [3072]
    const float* Wo     = (const float*)d_in[3];   // [1024,1024]
    const float* bo     = (const float*)d_in[4];   // [1024]
    const float* rope   = (const float*)d_in[5];   // [256,32,2]
    float* out = (float*)d_out;                    // [2,2048,1024] fp32

    char* ws = (char*)d_ws;
    __bf16* A1  = (__bf16*)(ws);                   //  8 MiB: hidden bf16 [4096][1024]
    __bf16* Wt  = (__bf16*)(ws + 8388608);         //  6 MiB: Wqkv^T bf16 [3072][1024]
    __bf16* Wot = (__bf16*)(ws + 14680064);        //  2 MiB: Wo^T bf16 [1024][1024]
    __bf16* Qb  = (__bf16*)(ws + 16777216);        //  8 MiB: Q [B][H][S][64]
    __bf16* Kb  = (__bf16*)(ws + 25165824);        //  8 MiB: K
    __bf16* Vb  = (__bf16*)(ws + 33554432);        //  8 MiB: V
    __bf16* AO  = (__bf16*)(ws + 41943040);        //  8 MiB: attn out [4096][1024]

    cast_f32_bf16<<<4096, 256, 0, stream>>>(hidden, A1, 1048576);
    transpose_cast<<<dim3(96, 32), dim3(32, 8), 0, stream>>>(Wqkv, Wt, 1024, 3072);
    transpose_cast<<<dim3(32, 32), dim3(32, 8), 0, stream>>>(Wo, Wot, 1024, 1024);

    // QKV projection (+fused RoPE): [4096,1024]@[1024,3072] -> Q/K/V [B][H][S][64]
    gemm_bt<128><<<32 * 24, 256, 0, stream>>>(A1, Wt, bqkv, rope, nullptr, Qb, Kb, Vb,
                                              4096, 3072, 1024, 1);
    // windowed attention -> AO [4096][1024] bf16
    attn_kernel<<<1024, 256, 0, stream>>>(Qb, Kb, Vb, AO);
    // output projection: [4096,1024]@[1024,1024] + bias -> d_out fp32 (TN=64: 512 blocks)
    gemm_bt<64><<<32 * 16, 256, 0, stream>>>(AO, Wot, bo, rope, out, nullptr, nullptr, nullptr,
                                             4096, 1024, 1024, 0);
}